// Round 1
// baseline (4498.957 us; speedup 1.0000x reference)
//
#include <hip/hip_runtime.h>
#include <math.h>

#define DIM     256
#define NROWS   32768
#define NCODES  8192
#define ZQ_ELEMS (NROWS * DIM)   // 8388608

// ---------------- numpy pairwise-sum replication (128-block, 8 accumulators) ---------------
// numpy: r[j] = a[j]; for i=8..120 step 8: r[j]+=a[i+j];
//        res = ((r0+r1)+(r2+r3))+((r4+r5)+(r6+r7))
// We sum fl(x*x), all ops pinned with __f*_rn to block fp-contract.
__device__ __forceinline__ float pw128_sq(const float* __restrict__ a) {
    float r[8];
#pragma unroll
    for (int j = 0; j < 8; ++j) r[j] = __fmul_rn(a[j], a[j]);
#pragma unroll
    for (int i = 8; i < 128; i += 8) {
#pragma unroll
        for (int j = 0; j < 8; ++j) r[j] = __fadd_rn(r[j], __fmul_rn(a[i + j], a[i + j]));
    }
    return __fadd_rn(__fadd_rn(__fadd_rn(r[0], r[1]), __fadd_rn(r[2], r[3])),
                     __fadd_rn(__fadd_rn(r[4], r[5]), __fadd_rn(r[6], r[7])));
}

// P[r] = np.sum(x*x, axis=1) for 256-wide rows: pairwise(128)+pairwise(128)
__global__ __launch_bounds__(256) void rowsq_kernel(const float* __restrict__ src,
                                                    float* __restrict__ dst) {
    __shared__ float tile[32][DIM + 1];
    const int row0 = blockIdx.x * 32;
    for (int e = threadIdx.x; e < 32 * DIM; e += 256) {
        int r = e >> 8, k = e & 255;
        tile[r][k] = src[(size_t)(row0 + r) * DIM + k];
    }
    __syncthreads();
    if (threadIdx.x < 32) {
        const float* a = tile[threadIdx.x];
        float s0 = pw128_sq(a);
        float s1 = pw128_sq(a + 128);
        dst[row0 + threadIdx.x] = __fadd_rn(s0, s1);
    }
}

// ---------------- main GEMM-argmin ----------------
// d[r,j] = fl( fl(P[r]+Q[j]) - 2*m ), m = ascending-k fmaf chain (BLAS micro-kernel order).
// WG: 64 rows x all codes (tiles of 64). LDS k-major, pitch 68 (16B-aligned float4,
// 2-way-max bank aliasing which is free). Thread tile 4 rows x 4 codes.
#define TM 64
#define TN 64
#define KP 68

__global__ __launch_bounds__(256, 1) void vq_argmin_kernel(
    const float* __restrict__ z, const float* __restrict__ w,
    const float* __restrict__ P, const float* __restrict__ Q,
    int* __restrict__ idx_i, float* __restrict__ idx_f) {
    extern __shared__ float lds[];
    float* As = lds;             // [DIM][KP]  As[k*KP + r]
    float* Bs = lds + DIM * KP;  // [DIM][KP]  Bs[k*KP + c]

    const int tid  = threadIdx.x;          // == k column for staging (blockDim == DIM)
    const int row0 = blockIdx.x * TM;
    const int rg   = tid >> 4;             // 0..15 -> rows rg*4..rg*4+3
    const int cg   = tid & 15;             // 0..15 -> codes cg*4..cg*4+3 within tile

    // stage A once (column k = tid)
#pragma unroll 4
    for (int i = 0; i < TM; ++i)
        As[tid * KP + i] = z[(size_t)(row0 + i) * DIM + tid];

    float Pr[4];
#pragma unroll
    for (int i = 0; i < 4; ++i) Pr[i] = P[row0 + rg * 4 + i];

    float bestD[4];
    int   bestI[4];
#pragma unroll
    for (int i = 0; i < 4; ++i) { bestD[i] = INFINITY; bestI[i] = 0; }

    for (int c0 = 0; c0 < NCODES; c0 += TN) {
        __syncthreads();   // protect previous tile's reads
#pragma unroll 4
        for (int i = 0; i < TN; ++i)
            Bs[tid * KP + i] = w[(size_t)(c0 + i) * DIM + tid];
        __syncthreads();

        float acc[4][4];
#pragma unroll
        for (int i = 0; i < 4; ++i)
#pragma unroll
            for (int j = 0; j < 4; ++j) acc[i][j] = 0.0f;

#pragma unroll 4
        for (int k = 0; k < DIM; ++k) {
            float av[4], bv[4];
            { float4 t = *(const float4*)&As[k * KP + rg * 4];
              av[0]=t.x; av[1]=t.y; av[2]=t.z; av[3]=t.w; }
            { float4 t = *(const float4*)&Bs[k * KP + cg * 4];
              bv[0]=t.x; bv[1]=t.y; bv[2]=t.z; bv[3]=t.w; }
#pragma unroll
            for (int i = 0; i < 4; ++i)
#pragma unroll
                for (int j = 0; j < 4; ++j)
                    acc[i][j] = fmaf(av[i], bv[j], acc[i][j]);
        }

        float qj[4];
        { float4 t = *(const float4*)&Q[c0 + cg * 4];
          qj[0]=t.x; qj[1]=t.y; qj[2]=t.z; qj[3]=t.w; }

#pragma unroll
        for (int i = 0; i < 4; ++i) {
#pragma unroll
            for (int j = 0; j < 4; ++j) {   // j ascending -> lowest index kept on ties
                float t1 = __fadd_rn(Pr[i], qj[j]);
                float d  = __fsub_rn(t1, __fmul_rn(2.0f, acc[i][j]));
                int code = c0 + cg * 4 + j;
                if (d < bestD[i]) { bestD[i] = d; bestI[i] = code; }
            }
        }
    }

    // reduce across the 16 cg lanes sharing each row group (lexicographic: d, then idx)
#pragma unroll
    for (int off = 1; off < 16; off <<= 1) {
#pragma unroll
        for (int i = 0; i < 4; ++i) {
            float od = __shfl_xor(bestD[i], off);
            int   oi = __shfl_xor(bestI[i], off);
            if (od < bestD[i] || (od == bestD[i] && oi < bestI[i])) {
                bestD[i] = od; bestI[i] = oi;
            }
        }
    }
    if (cg == 0) {
#pragma unroll
        for (int i = 0; i < 4; ++i) {
            int row = row0 + rg * 4 + i;
            idx_i[row] = bestI[i];
            idx_f[row] = (float)bestI[i];
        }
    }
}

// ---------------- gather z_q, write z_q_st, loss partials ----------------
__global__ __launch_bounds__(256) void gather_loss_kernel(
    const float* __restrict__ z, const float* __restrict__ w,
    const int* __restrict__ idx_i, float* __restrict__ zq_out,
    double* __restrict__ partial) {
    __shared__ double red[256];
    const int t    = blockIdx.x * 256 + threadIdx.x;
    const int base = t * 4;                 // exact cover: 8192*256*4 == ZQ_ELEMS
    const int row  = base >> 8;
    const int c    = base & 255;
    const int code = idx_i[row];
    float4 zv = *(const float4*)&z[base];
    float4 wv = *(const float4*)&w[(size_t)code * DIM + c];
    float zz[4] = { zv.x, zv.y, zv.z, zv.w };
    float ww[4] = { wv.x, wv.y, wv.z, wv.w };
    float o[4];
    double s = 0.0;
#pragma unroll
    for (int j = 0; j < 4; ++j) {
        float diff = __fsub_rn(ww[j], zz[j]);   // fl(z_q - z)
        o[j] = __fadd_rn(zz[j], diff);          // z_q_st = fl(z + fl(z_q - z))
        double dd = (double)diff;
        s += dd * dd;
    }
    *(float4*)&zq_out[base] = make_float4(o[0], o[1], o[2], o[3]);
    red[threadIdx.x] = s;
    __syncthreads();
    for (int st = 128; st > 0; st >>= 1) {
        if (threadIdx.x < st) red[threadIdx.x] += red[threadIdx.x + st];
        __syncthreads();
    }
    if (threadIdx.x == 0) partial[blockIdx.x] = red[0];
}

__global__ __launch_bounds__(256) void loss_final_kernel(const double* __restrict__ partial,
                                                         float* __restrict__ loss_out) {
    __shared__ double red[256];
    double s = 0.0;
    for (int i = threadIdx.x; i < 8192; i += 256) s += partial[i];
    red[threadIdx.x] = s;
    __syncthreads();
    for (int st = 128; st > 0; st >>= 1) {
        if (threadIdx.x < st) red[threadIdx.x] += red[threadIdx.x + st];
        __syncthreads();
    }
    if (threadIdx.x == 0)
        loss_out[0] = (float)(1.25 * red[0] / (double)ZQ_ELEMS);
}

extern "C" void kernel_launch(void* const* d_in, const int* in_sizes, int n_in,
                              void* d_out, int out_size, void* d_ws, size_t ws_size,
                              hipStream_t stream) {
    const float* z = (const float*)d_in[0];   // [32768, 256]
    const float* w = (const float*)d_in[1];   // [8192, 256]
    float* out = (float*)d_out;               // [zq 8388608][loss 1][idx 32768]

    float*  P       = (float*)d_ws;           // 32768 f32
    float*  Q       = P + NROWS;              // 8192 f32
    int*    idx_i   = (int*)(Q + NCODES);     // 32768 i32
    double* partial = (double*)(idx_i + NROWS); // 8192 f64 (byte off 294912, 8B aligned)

    rowsq_kernel<<<NROWS / 32, 256, 0, stream>>>(z, P);
    rowsq_kernel<<<NCODES / 32, 256, 0, stream>>>(w, Q);

    size_t ldsBytes = (size_t)2 * DIM * KP * sizeof(float);  // 139264 B
    vq_argmin_kernel<<<NROWS / TM, 256, ldsBytes, stream>>>(
        z, w, P, Q, idx_i, out + ZQ_ELEMS + 1);

    gather_loss_kernel<<<ZQ_ELEMS / (256 * 4), 256, 0, stream>>>(z, w, idx_i, out, partial);
    loss_final_kernel<<<1, 256, 0, stream>>>(partial, out + ZQ_ELEMS);
}

// Round 2
// 2370.764 us; speedup vs baseline: 1.8977x; 1.8977x over previous
//
#include <hip/hip_runtime.h>
#include <math.h>

#define DIM     256
#define NROWS   32768
#define NCODES  8192
#define ZQ_ELEMS (NROWS * DIM)   // 8388608

// ---------------- numpy pairwise-sum replication (128-block, 8 accumulators) ---------------
__device__ __forceinline__ float pw128_sq(const float* __restrict__ a) {
    float r[8];
#pragma unroll
    for (int j = 0; j < 8; ++j) r[j] = __fmul_rn(a[j], a[j]);
#pragma unroll
    for (int i = 8; i < 128; i += 8) {
#pragma unroll
        for (int j = 0; j < 8; ++j) r[j] = __fadd_rn(r[j], __fmul_rn(a[i + j], a[i + j]));
    }
    return __fadd_rn(__fadd_rn(__fadd_rn(r[0], r[1]), __fadd_rn(r[2], r[3])),
                     __fadd_rn(__fadd_rn(r[4], r[5]), __fadd_rn(r[6], r[7])));
}

__global__ __launch_bounds__(256) void rowsq_kernel(const float* __restrict__ src,
                                                    float* __restrict__ dst) {
    __shared__ float tile[32][DIM + 1];
    const int row0 = blockIdx.x * 32;
    for (int e = threadIdx.x; e < 32 * DIM; e += 256) {
        int r = e >> 8, k = e & 255;
        tile[r][k] = src[(size_t)(row0 + r) * DIM + k];
    }
    __syncthreads();
    if (threadIdx.x < 32) {
        const float* a = tile[threadIdx.x];
        float s0 = pw128_sq(a);
        float s1 = pw128_sq(a + 128);
        dst[row0 + threadIdx.x] = __fadd_rn(s0, s1);
    }
}

// ---------------- main GEMM-argmin (partial over a column range) ----------------
// Exact semantics preserved: m(r,c) = single ascending-k fmaf chain (acc carries
// across BK chunks), d = fl( fl(P+Q) - fl(2*m) ).
#define BM 128
#define BN 128
#define BK 32
#define PITCH 132            // words; 16B-aligned float4 rows, 2-way max aliasing on reads
#define NCB 4                // column-range partitions
#define COLS_PER_CB (NCODES / NCB)   // 2048

__global__ __launch_bounds__(256, 4) void vq_partial_kernel(
    const float* __restrict__ z, const float* __restrict__ w,
    const float* __restrict__ P, const float* __restrict__ Q,
    float* __restrict__ cand_d, int* __restrict__ cand_i) {
    __shared__ float As[BK][PITCH];
    __shared__ float Bs[BK][PITCH];

    const int tid  = threadIdx.x;
    const int rb   = blockIdx.x >> 2;          // 0..255
    const int cb   = blockIdx.x & 3;           // 0..3
    const int row0 = rb * BM;
    const int colbase = cb * COLS_PER_CB;
    const int rg = tid >> 4;                   // 0..15 -> rows rg*8..rg*8+7
    const int cg = tid & 15;                   // 0..15 -> cols cg*4..+3 and 64+cg*4..+3

    float Pr[8];
#pragma unroll
    for (int i = 0; i < 8; ++i) Pr[i] = P[row0 + rg * 8 + i];

    float bestD[8];
    int   bestI[8];
#pragma unroll
    for (int i = 0; i < 8; ++i) { bestD[i] = INFINITY; bestI[i] = 0; }

    for (int ct = 0; ct < COLS_PER_CB; ct += BN) {
        const int c0 = colbase + ct;
        float acc[8][8];
#pragma unroll
        for (int i = 0; i < 8; ++i)
#pragma unroll
            for (int j = 0; j < 8; ++j) acc[i][j] = 0.0f;

        for (int kc = 0; kc < DIM; kc += BK) {
            __syncthreads();   // previous-chunk reads done
#pragma unroll
            for (int it = 0; it < 4; ++it) {
                int u  = it * 256 + tid;
                int r  = u >> 3;               // 0..127
                int kg = u & 7;                // 0..7 (4 floats each)
                float4 a = *(const float4*)&z[(size_t)(row0 + r) * DIM + kc + kg * 4];
                As[kg * 4 + 0][r] = a.x; As[kg * 4 + 1][r] = a.y;
                As[kg * 4 + 2][r] = a.z; As[kg * 4 + 3][r] = a.w;
                float4 b = *(const float4*)&w[(size_t)(c0 + r) * DIM + kc + kg * 4];
                Bs[kg * 4 + 0][r] = b.x; Bs[kg * 4 + 1][r] = b.y;
                Bs[kg * 4 + 2][r] = b.z; Bs[kg * 4 + 3][r] = b.w;
            }
            __syncthreads();

#pragma unroll
            for (int k = 0; k < BK; ++k) {
                float av[8], bv[8];
                { float4 t = *(const float4*)&As[k][rg * 8];
                  av[0]=t.x; av[1]=t.y; av[2]=t.z; av[3]=t.w; }
                { float4 t = *(const float4*)&As[k][rg * 8 + 4];
                  av[4]=t.x; av[5]=t.y; av[6]=t.z; av[7]=t.w; }
                { float4 t = *(const float4*)&Bs[k][cg * 4];
                  bv[0]=t.x; bv[1]=t.y; bv[2]=t.z; bv[3]=t.w; }
                { float4 t = *(const float4*)&Bs[k][cg * 4 + 64];
                  bv[4]=t.x; bv[5]=t.y; bv[6]=t.z; bv[7]=t.w; }
#pragma unroll
                for (int i = 0; i < 8; ++i)
#pragma unroll
                    for (int j = 0; j < 8; ++j)
                        acc[i][j] = fmaf(av[i], bv[j], acc[i][j]);
            }
        }

        float qv[8];
        { float4 t = *(const float4*)&Q[c0 + cg * 4];
          qv[0]=t.x; qv[1]=t.y; qv[2]=t.z; qv[3]=t.w; }
        { float4 t = *(const float4*)&Q[c0 + 64 + cg * 4];
          qv[4]=t.x; qv[5]=t.y; qv[6]=t.z; qv[7]=t.w; }

#pragma unroll
        for (int i = 0; i < 8; ++i) {
#pragma unroll
            for (int j = 0; j < 8; ++j) {   // ascending code order within thread
                float d = __fsub_rn(__fadd_rn(Pr[i], qv[j]), __fmul_rn(2.0f, acc[i][j]));
                int code = c0 + ((j < 4) ? (cg * 4 + j) : (64 + cg * 4 + (j - 4)));
                if (d < bestD[i]) { bestD[i] = d; bestI[i] = code; }
            }
        }
    }

    // reduce across the 16 cg lanes sharing each row group (lexicographic: d, then idx)
#pragma unroll
    for (int off = 1; off < 16; off <<= 1) {
#pragma unroll
        for (int i = 0; i < 8; ++i) {
            float od = __shfl_xor(bestD[i], off);
            int   oi = __shfl_xor(bestI[i], off);
            if (od < bestD[i] || (od == bestD[i] && oi < bestI[i])) {
                bestD[i] = od; bestI[i] = oi;
            }
        }
    }
    if (cg == 0) {
#pragma unroll
        for (int i = 0; i < 8; ++i) {
            int row = row0 + rg * 8 + i;
            cand_d[cb * NROWS + row] = bestD[i];
            cand_i[cb * NROWS + row] = bestI[i];
        }
    }
}

// merge the NCB per-range candidates per row (lexicographic -> exact argmin semantics)
__global__ __launch_bounds__(256) void argmin_reduce_kernel(
    const float* __restrict__ cand_d, const int* __restrict__ cand_i,
    int* __restrict__ idx_i, float* __restrict__ idx_f) {
    const int row = blockIdx.x * 256 + threadIdx.x;
    float bd = cand_d[row];
    int   bi = cand_i[row];
#pragma unroll
    for (int cb = 1; cb < NCB; ++cb) {
        float d = cand_d[cb * NROWS + row];
        int   ii = cand_i[cb * NROWS + row];
        if (d < bd || (d == bd && ii < bi)) { bd = d; bi = ii; }
    }
    idx_i[row] = bi;
    idx_f[row] = (float)bi;
}

// ---------------- gather z_q, write z_q_st, loss partials ----------------
__global__ __launch_bounds__(256) void gather_loss_kernel(
    const float* __restrict__ z, const float* __restrict__ w,
    const int* __restrict__ idx_i, float* __restrict__ zq_out,
    double* __restrict__ partial) {
    __shared__ double red[256];
    const int t    = blockIdx.x * 256 + threadIdx.x;
    const int base = t * 4;
    const int row  = base >> 8;
    const int c    = base & 255;
    const int code = idx_i[row];
    float4 zv = *(const float4*)&z[base];
    float4 wv = *(const float4*)&w[(size_t)code * DIM + c];
    float zz[4] = { zv.x, zv.y, zv.z, zv.w };
    float ww[4] = { wv.x, wv.y, wv.z, wv.w };
    float o[4];
    double s = 0.0;
#pragma unroll
    for (int j = 0; j < 4; ++j) {
        float diff = __fsub_rn(ww[j], zz[j]);
        o[j] = __fadd_rn(zz[j], diff);
        double dd = (double)diff;
        s += dd * dd;
    }
    *(float4*)&zq_out[base] = make_float4(o[0], o[1], o[2], o[3]);
    red[threadIdx.x] = s;
    __syncthreads();
    for (int st = 128; st > 0; st >>= 1) {
        if (threadIdx.x < st) red[threadIdx.x] += red[threadIdx.x + st];
        __syncthreads();
    }
    if (threadIdx.x == 0) partial[blockIdx.x] = red[0];
}

__global__ __launch_bounds__(256) void loss_final_kernel(const double* __restrict__ partial,
                                                         float* __restrict__ loss_out) {
    __shared__ double red[256];
    double s = 0.0;
    for (int i = threadIdx.x; i < 8192; i += 256) s += partial[i];
    red[threadIdx.x] = s;
    __syncthreads();
    for (int st = 128; st > 0; st >>= 1) {
        if (threadIdx.x < st) red[threadIdx.x] += red[threadIdx.x + st];
        __syncthreads();
    }
    if (threadIdx.x == 0)
        loss_out[0] = (float)(1.25 * red[0] / (double)ZQ_ELEMS);
}

extern "C" void kernel_launch(void* const* d_in, const int* in_sizes, int n_in,
                              void* d_out, int out_size, void* d_ws, size_t ws_size,
                              hipStream_t stream) {
    const float* z = (const float*)d_in[0];   // [32768, 256]
    const float* w = (const float*)d_in[1];   // [8192, 256]
    float* out = (float*)d_out;               // [zq 8388608][loss 1][idx 32768]

    float*  P       = (float*)d_ws;               // 32768 f32
    float*  Q       = P + NROWS;                  // 8192 f32
    int*    idx_i   = (int*)(Q + NCODES);         // 32768 i32
    double* partial = (double*)(idx_i + NROWS);   // 8192 f64 (8B aligned)
    float*  cand_d  = (float*)(partial + 8192);   // 4*32768 f32
    int*    cand_i  = (int*)(cand_d + NCB * NROWS); // 4*32768 i32

    rowsq_kernel<<<NROWS / 32, 256, 0, stream>>>(z, P);
    rowsq_kernel<<<NCODES / 32, 256, 0, stream>>>(w, Q);

    vq_partial_kernel<<<(NROWS / BM) * NCB, 256, 0, stream>>>(z, w, P, Q, cand_d, cand_i);
    argmin_reduce_kernel<<<NROWS / 256, 256, 0, stream>>>(cand_d, cand_i, idx_i,
                                                          out + ZQ_ELEMS + 1);

    gather_loss_kernel<<<ZQ_ELEMS / (256 * 4), 256, 0, stream>>>(z, w, idx_i, out, partial);
    loss_final_kernel<<<1, 256, 0, stream>>>(partial, out + ZQ_ELEMS);
}